// Round 1
// baseline (255.842 us; speedup 1.0000x reference)
//
#include <hip/hip_runtime.h>

// Shapes (fixed by the reference):
//   prev_feat/next_feat: [8, 32, 48, 48, 48] f32
//   phi:                 [8, 1, 96, 96, 96] f32
//   stream:              [8, 3, 96, 96, 96] f32
// Outputs (concatenated flat in d_out, f32):
//   corr       [8, 27, 48, 48, 48]  = 23,887,872
//   vel        [8, 3, 94, 94, 94]   = 19,934,016
//   vel_phi    [8, 3, 94, 94, 94]
//   vel_stream [8, 3, 94, 94, 94]

constexpr int CB = 8, CC = 32, CX = 48, CY = 48, CZ = 48;
constexpr int H = 96, O = 94;

// ---------------------------------------------------------------------------
// corr: only 9 distinct (dx,dy) correlations; the 3 k-groups differ only by
// zeroing z==CZ-1 (k=-1) or z==0 (k=+1). float4 along z (16B aligned for all
// taps since shifts are in x/y only).
// ---------------------------------------------------------------------------
__global__ __launch_bounds__(256) void corr_kernel(
    const float* __restrict__ prev, const float* __restrict__ nxt,
    float* __restrict__ corr)
{
    constexpr int Z4 = CZ / 4;          // 12
    int idx = blockIdx.x * 256 + threadIdx.x;   // total = 8*48*48*12 = 221184 (exact)
    int z4 = idx % Z4; int r = idx / Z4;
    int y = r % CY; r /= CY;
    int x = r % CX; int b = r / CX;

    const int plane = CY * CZ;          // 2304
    const int cstr  = CX * plane;       // 110592
    const size_t bbase = (size_t)b * CC * cstr;

    const float* pp = prev + bbase + (size_t)x * plane + (size_t)y * CZ + z4 * 4;

    const float* tp[9];
    bool ok[9];
#pragma unroll
    for (int dx = -1; dx <= 1; ++dx) {
#pragma unroll
        for (int dy = -1; dy <= 1; ++dy) {
            const int jj = (dx + 1) * 3 + (dy + 1);
            int xx = x + dx, yy = y + dy;
            bool v = (xx >= 0) && (xx < CX) && (yy >= 0) && (yy < CY);
            ok[jj] = v;
            tp[jj] = nxt + bbase + (size_t)(v ? xx : x) * plane
                                 + (size_t)(v ? yy : y) * CZ + z4 * 4;
        }
    }

    float a0[9], a1[9], a2[9], a3[9];
#pragma unroll
    for (int jj = 0; jj < 9; ++jj) { a0[jj] = a1[jj] = a2[jj] = a3[jj] = 0.f; }

#pragma unroll 2
    for (int c = 0; c < CC; ++c) {
        float4 pv = *reinterpret_cast<const float4*>(pp);
#pragma unroll
        for (int jj = 0; jj < 9; ++jj) {
            if (ok[jj]) {
                float4 nv = *reinterpret_cast<const float4*>(tp[jj]);
                a0[jj] = fmaf(pv.x, nv.x, a0[jj]);
                a1[jj] = fmaf(pv.y, nv.y, a1[jj]);
                a2[jj] = fmaf(pv.z, nv.z, a2[jj]);
                a3[jj] = fmaf(pv.w, nv.w, a3[jj]);
            }
            tp[jj] += cstr;
        }
        pp += cstr;
    }

    const size_t obase = (size_t)b * 27 * cstr + (size_t)x * plane
                       + (size_t)y * CZ + z4 * 4;
    const float s = 1.0f / 32.0f;
#pragma unroll
    for (int jj = 0; jj < 9; ++jj) {
        float r0 = a0[jj] * s, r1 = a1[jj] * s, r2 = a2[jj] * s, r3 = a3[jj] * s;
        // k = -1 group (ch jj): zero the z==47 element
        float4 g0 = make_float4(r0, r1, r2, (z4 == Z4 - 1) ? 0.f : r3);
        *reinterpret_cast<float4*>(corr + obase + (size_t)jj * cstr) = g0;
        // k = 0 group (ch 9+jj): unmasked
        float4 g1 = make_float4(r0, r1, r2, r3);
        *reinterpret_cast<float4*>(corr + obase + (size_t)(9 + jj) * cstr) = g1;
        // k = +1 group (ch 18+jj): zero the z==0 element
        float4 g2 = make_float4((z4 == 0) ? 0.f : r0, r1, r2, r3);
        *reinterpret_cast<float4*>(corr + obase + (size_t)(18 + jj) * cstr) = g2;
    }
}

// ---------------------------------------------------------------------------
// vel: closed-form stencils. All indices stay within [0,96); no _fdiff
// edge case or pad reaches the cropped 94^3 output.
// ---------------------------------------------------------------------------
__global__ __launch_bounds__(256) void vel_kernel(
    const float* __restrict__ phi, const float* __restrict__ stm,
    float* __restrict__ vel, float* __restrict__ vphi, float* __restrict__ vstr)
{
    int idx = blockIdx.x * 256 + threadIdx.x;
    const int total = CB * O * O * O;            // 6,644,672
    if (idx >= total) return;
    int t = idx % O; int r = idx / O;
    int j = r % O; r /= O;
    int i = r % O; int b = r / O;

    const int hp = H * H;                        // 9216
    const size_t hc = (size_t)H * hp;            // 884736
    const float* ph = phi + (size_t)b * hc;
    const float* s0 = stm + (size_t)b * 3 * hc;
    const float* s1 = s0 + hc;
    const float* s2 = s1 + hc;

#define AT(p, A, B_, C_) (p)[(size_t)(A) * hp + (size_t)(B_) * H + (C_)]

    // phi velocity (diff then 2-tap average == central difference; keep ref order)
    float pc = AT(ph, i + 1, j + 1, t + 1);
    float mu_p = ((AT(ph, i + 1, j + 1, t + 2) - pc) + (pc - AT(ph, i + 1, j + 1, t))) * 0.5f;
    float mv_p = ((AT(ph, i + 1, j + 2, t + 1) - pc) + (pc - AT(ph, i + 1, j,     t + 1))) * 0.5f;
    float mw_p = ((AT(ph, i + 2, j + 1, t + 1) - pc) + (pc - AT(ph, i,     j + 1, t + 1))) * 0.5f;

    // stream velocity: u = d_x s1 - d_y s0 ; v = d_t s0 - d_x s2 ; w = d_y s2 - d_t s1
    float u1 = (AT(s1, i + 2, j + 1, t + 1) - AT(s1, i + 1, j + 1, t + 1))
             - (AT(s0, i + 1, j + 2, t + 1) - AT(s0, i + 1, j + 1, t + 1));
    float u0 = (AT(s1, i + 2, j + 1, t    ) - AT(s1, i + 1, j + 1, t    ))
             - (AT(s0, i + 1, j + 2, t    ) - AT(s0, i + 1, j + 1, t    ));
    float mu_s = (u1 + u0) * 0.5f;

    float v1 = (AT(s0, i + 1, j + 1, t + 2) - AT(s0, i + 1, j + 1, t + 1))
             - (AT(s2, i + 2, j + 1, t + 1) - AT(s2, i + 1, j + 1, t + 1));
    float v0 = (AT(s0, i + 1, j,     t + 2) - AT(s0, i + 1, j,     t + 1))
             - (AT(s2, i + 2, j,     t + 1) - AT(s2, i + 1, j,     t + 1));
    float mv_s = (v1 + v0) * 0.5f;

    float w1 = (AT(s2, i + 1, j + 2, t + 1) - AT(s2, i + 1, j + 1, t + 1))
             - (AT(s1, i + 1, j + 1, t + 2) - AT(s1, i + 1, j + 1, t + 1));
    float w0 = (AT(s2, i,     j + 2, t + 1) - AT(s2, i,     j + 1, t + 1))
             - (AT(s1, i,     j + 1, t + 2) - AT(s1, i,     j + 1, t + 1));
    float mw_s = (w1 + w0) * 0.5f;
#undef AT

    const size_t oc = (size_t)O * O * O;         // 830584
    const size_t o  = ((size_t)i * O + j) * O + t;
    const size_t b3 = (size_t)b * 3;
    vphi[(b3 + 0) * oc + o] = mu_p;
    vphi[(b3 + 1) * oc + o] = mv_p;
    vphi[(b3 + 2) * oc + o] = mw_p;
    vstr[(b3 + 0) * oc + o] = mu_s;
    vstr[(b3 + 1) * oc + o] = mv_s;
    vstr[(b3 + 2) * oc + o] = mw_s;
    vel [(b3 + 0) * oc + o] = mu_p + mu_s;
    vel [(b3 + 1) * oc + o] = mv_p + mv_s;
    vel [(b3 + 2) * oc + o] = mw_p + mw_s;
}

extern "C" void kernel_launch(void* const* d_in, const int* in_sizes, int n_in,
                              void* d_out, int out_size, void* d_ws, size_t ws_size,
                              hipStream_t stream)
{
    const float* prev = (const float*)d_in[0];
    const float* nxt  = (const float*)d_in[1];
    const float* phi  = (const float*)d_in[2];
    const float* stm  = (const float*)d_in[3];
    // d_in[4..6] are out_h/out_w/out_t scalars (= 94, fixed); shapes hard-coded.

    float* out = (float*)d_out;
    const size_t corr_sz = (size_t)CB * 27 * CX * CY * CZ;   // 23,887,872
    const size_t vel_sz  = (size_t)CB * 3 * O * O * O;       // 19,934,016
    float* corr = out;
    float* vel  = out + corr_sz;
    float* vphi = vel + vel_sz;
    float* vstr = vphi + vel_sz;

    {
        const int total = CB * CX * CY * (CZ / 4);           // 221,184
        corr_kernel<<<total / 256, 256, 0, stream>>>(prev, nxt, corr);
    }
    {
        const int total = CB * O * O * O;                    // 6,644,672
        const int blocks = (total + 255) / 256;
        vel_kernel<<<blocks, 256, 0, stream>>>(phi, stm, vel, vphi, vstr);
    }
}

// Round 2
// 207.298 us; speedup vs baseline: 1.2342x; 1.2342x over previous
//
#include <hip/hip_runtime.h>

// Shapes (fixed):
//   prev/next: [8, 32, 48, 48, 48] f32
//   phi:       [8, 1, 96, 96, 96] f32
//   stream:    [8, 3, 96, 96, 96] f32
// Outputs concatenated in d_out (f32): corr [8,27,48^3], vel/vel_phi/vel_stream [8,3,94^3]

typedef float f2 __attribute__((ext_vector_type(2)));

constexpr int CB = 8, CC = 32, CX = 48, CY = 48, CZ = 48;
constexpr int H = 96, O = 94;

// ---------------------------------------------------------------------------
// corr: 9 distinct (dx,dy) correlations, written 3x with z-edge masks.
// z-granularity 2 (f2) for 6.75 waves/SIMD. XCD swizzle: 1728 blocks, 216 per
// XCD == exactly one batch b per XCD -> per-XCD c-sweep working set is one
// 442 KB nxt slab (L2-resident) -> nxt ~1x from HBM. nt stores keep the
// 95.5 MB output stream out of L2.
// ---------------------------------------------------------------------------
__global__ __launch_bounds__(256) void corr_kernel(
    const float* __restrict__ prev, const float* __restrict__ nxt,
    float* __restrict__ corr)
{
    constexpr int Z2 = CZ / 2;                       // 24
    constexpr int NWG = (CB * CX * CY * Z2) / 256;   // 1728 (exact)
    int bid = blockIdx.x;
    int swz = (bid & 7) * (NWG / 8) + (bid >> 3);    // XCD k -> b = k
    int idx = swz * 256 + (int)threadIdx.x;
    int z2 = idx % Z2; int r = idx / Z2;
    int y = r % CY; r /= CY;
    int x = r % CX; int b = r / CX;

    const int plane = CY * CZ;                       // 2304
    const int cstr  = CX * plane;                    // 110592
    const size_t bbase = (size_t)b * CC * cstr;

    const float* pp = prev + bbase + (size_t)x * plane + (size_t)y * CZ + z2 * 2;

    const float* tpx[3];
    bool okx[3], oky[3];
#pragma unroll
    for (int d = 0; d < 3; ++d) {
        int xx = x + d - 1;
        okx[d] = (unsigned)xx < (unsigned)CX;
        tpx[d] = nxt + bbase + (size_t)(okx[d] ? xx : x) * plane
                             + (size_t)y * CZ + z2 * 2;
        int yy = y + d - 1;
        oky[d] = (unsigned)yy < (unsigned)CY;
    }
    bool okj[9];
#pragma unroll
    for (int a = 0; a < 3; ++a)
#pragma unroll
        for (int dyy = 0; dyy < 3; ++dyy) okj[a * 3 + dyy] = okx[a] && oky[dyy];

    f2 acc[9];
#pragma unroll
    for (int jj = 0; jj < 9; ++jj) acc[jj] = f2{0.f, 0.f};

#pragma unroll 2
    for (int c = 0; c < CC; ++c) {
        f2 pv = *reinterpret_cast<const f2*>(pp);
#pragma unroll
        for (int a = 0; a < 3; ++a) {
#pragma unroll
            for (int dyy = 0; dyy < 3; ++dyy) {
                const int jj = a * 3 + dyy;
                if (okj[jj]) {
                    f2 nv = *reinterpret_cast<const f2*>(tpx[a] + (dyy - 1) * CZ);
                    acc[jj] += pv * nv;
                }
            }
            tpx[a] += cstr;
        }
        pp += cstr;
    }

    const size_t obase = (size_t)b * 27 * cstr + (size_t)x * plane
                       + (size_t)y * CZ + z2 * 2;
    const float s = 1.0f / 32.0f;
#pragma unroll
    for (int jj = 0; jj < 9; ++jj) {
        f2 v = acc[jj] * s;
        f2 gm = v; if (z2 == Z2 - 1) gm.y = 0.f;     // k=-1: zero z==47
        f2 gp = v; if (z2 == 0)      gp.x = 0.f;     // k=+1: zero z==0
        __builtin_nontemporal_store(gm, (f2*)(corr + obase + (size_t)jj * cstr));
        __builtin_nontemporal_store(v,  (f2*)(corr + obase + (size_t)(9 + jj) * cstr));
        __builtin_nontemporal_store(gp, (f2*)(corr + obase + (size_t)(18 + jj) * cstr));
    }
}

// ---------------------------------------------------------------------------
// vel: 2 consecutive t-outputs per thread. All row strides (376 B) and bases
// are 8B-aligned -> f2 loads/stores legal everywhere. nt stores (239 MB).
// ---------------------------------------------------------------------------
__global__ __launch_bounds__(256) void vel_kernel(
    const float* __restrict__ phi, const float* __restrict__ stm,
    float* __restrict__ vel, float* __restrict__ vphi, float* __restrict__ vstr)
{
    constexpr int TT = O / 2;                        // 47
    const int total = CB * O * O * TT;               // 3,322,336
    const int nwg = (total + 255) / 256;             // 12978
    const int q = nwg >> 3, rr = nwg & 7;            // 1622, 2
    int bid = blockIdx.x;
    int xcd = bid & 7, g = bid >> 3;
    int swz = (xcd < rr) ? (xcd * (q + 1) + g) : (rr * (q + 1) + (xcd - rr) * q + g);
    int idx = swz * 256 + (int)threadIdx.x;
    if (idx >= total) return;
    int tt = idx % TT; int r2 = idx / TT;
    int j = r2 % O; r2 /= O;
    int i = r2 % O; int b = r2 / O;
    const int t = tt * 2;

    const int hp = H * H;                            // 9216
    const size_t hc = (size_t)H * hp;
    const float* ph = phi + (size_t)b * hc;
    const float* s0 = stm + (size_t)b * 3 * hc;
    const float* s1 = s0 + hc;
    const float* s2 = s1 + hc;

#define R(A, B_) ((size_t)(A) * hp + (size_t)(B_) * H + t)

    // ---- phi taps ----
    const float* p11 = ph + R(i + 1, j + 1);
    f2 p11a = *(const f2*)p11;           // t, t+1
    f2 p11b = *(const f2*)(p11 + 2);     // t+2, t+3
    float p12_1 = ph[R(i + 1, j + 2) + 1], p12_2 = ph[R(i + 1, j + 2) + 2];
    float p10_1 = ph[R(i + 1, j)     + 1], p10_2 = ph[R(i + 1, j)     + 2];
    float p21_1 = ph[R(i + 2, j + 1) + 1], p21_2 = ph[R(i + 2, j + 1) + 2];
    float p01_1 = ph[R(i,     j + 1) + 1], p01_2 = ph[R(i,     j + 1) + 2];

    float pc0 = p11a.y, pc1 = p11b.x;
    float mup0 = ((p11b.x - pc0) + (pc0 - p11a.x)) * 0.5f;
    float mup1 = ((p11b.y - pc1) + (pc1 - p11a.y)) * 0.5f;
    float mvp0 = ((p12_1 - pc0) + (pc0 - p10_1)) * 0.5f;
    float mvp1 = ((p12_2 - pc1) + (pc1 - p10_2)) * 0.5f;
    float mwp0 = ((p21_1 - pc0) + (pc0 - p01_1)) * 0.5f;
    float mwp1 = ((p21_2 - pc1) + (pc1 - p01_2)) * 0.5f;

    // ---- stream taps ----
    const float* q1_11 = s1 + R(i + 1, j + 1);
    f2 s1_11a = *(const f2*)q1_11;  f2 s1_11b = *(const f2*)(q1_11 + 2);
    const float* q1_21 = s1 + R(i + 2, j + 1);
    f2 s1_21a = *(const f2*)q1_21;  float s1_21_2 = q1_21[2];
    const float* q1_01 = s1 + R(i, j + 1);
    float s1_01_1 = q1_01[1];       f2 s1_01b = *(const f2*)(q1_01 + 2);

    const float* q0_11 = s0 + R(i + 1, j + 1);
    f2 s0_11a = *(const f2*)q0_11;  f2 s0_11b = *(const f2*)(q0_11 + 2);
    const float* q0_12 = s0 + R(i + 1, j + 2);
    f2 s0_12a = *(const f2*)q0_12;  float s0_12_2 = q0_12[2];
    const float* q0_10 = s0 + R(i + 1, j);
    float s0_10_1 = q0_10[1];       f2 s0_10b = *(const f2*)(q0_10 + 2);

    float s2_21_1 = s2[R(i + 2, j + 1) + 1], s2_21_2 = s2[R(i + 2, j + 1) + 2];
    float s2_11_1 = s2[R(i + 1, j + 1) + 1], s2_11_2 = s2[R(i + 1, j + 1) + 2];
    float s2_20_1 = s2[R(i + 2, j)     + 1], s2_20_2 = s2[R(i + 2, j)     + 2];
    float s2_10_1 = s2[R(i + 1, j)     + 1], s2_10_2 = s2[R(i + 1, j)     + 2];
    float s2_12_1 = s2[R(i + 1, j + 2) + 1], s2_12_2 = s2[R(i + 1, j + 2) + 2];
    float s2_02_1 = s2[R(i,     j + 2) + 1], s2_02_2 = s2[R(i,     j + 2) + 2];
    float s2_01_1 = s2[R(i,     j + 1) + 1], s2_01_2 = s2[R(i,     j + 1) + 2];
#undef R

    // u = d_x s1 - d_y s0 ; mu = (u(t+1)+u(t))/2
    float u0 = (s1_21a.x - s1_11a.x) - (s0_12a.x - s0_11a.x);
    float u1 = (s1_21a.y - s1_11a.y) - (s0_12a.y - s0_11a.y);
    float u2 = (s1_21_2  - s1_11b.x) - (s0_12_2  - s0_11b.x);
    float mus0 = (u1 + u0) * 0.5f;
    float mus1 = (u2 + u1) * 0.5f;

    // v = d_t s0 - d_x s2 ; mv = (v(j+1)+v(j))/2
    float v1_0 = (s0_11b.x - s0_11a.y) - (s2_21_1 - s2_11_1);
    float v0_0 = (s0_10b.x - s0_10_1)  - (s2_20_1 - s2_10_1);
    float mvs0 = (v1_0 + v0_0) * 0.5f;
    float v1_1 = (s0_11b.y - s0_11b.x) - (s2_21_2 - s2_11_2);
    float v0_1 = (s0_10b.y - s0_10b.x) - (s2_20_2 - s2_10_2);
    float mvs1 = (v1_1 + v0_1) * 0.5f;

    // w = d_y s2 - d_t s1 ; mw = (w(i+1)+w(i))/2
    float w1_0 = (s2_12_1 - s2_11_1) - (s1_11b.x - s1_11a.y);
    float w0_0 = (s2_02_1 - s2_01_1) - (s1_01b.x - s1_01_1);
    float mws0 = (w1_0 + w0_0) * 0.5f;
    float w1_1 = (s2_12_2 - s2_11_2) - (s1_11b.y - s1_11b.x);
    float w0_1 = (s2_02_2 - s2_01_2) - (s1_01b.y - s1_01b.x);
    float mws1 = (w1_1 + w0_1) * 0.5f;

    const size_t oc = (size_t)O * O * O;
    const size_t o  = ((size_t)i * O + j) * O + t;
    const size_t b3 = (size_t)b * 3;
    __builtin_nontemporal_store(f2{mup0, mup1}, (f2*)(vphi + (b3 + 0) * oc + o));
    __builtin_nontemporal_store(f2{mvp0, mvp1}, (f2*)(vphi + (b3 + 1) * oc + o));
    __builtin_nontemporal_store(f2{mwp0, mwp1}, (f2*)(vphi + (b3 + 2) * oc + o));
    __builtin_nontemporal_store(f2{mus0, mus1}, (f2*)(vstr + (b3 + 0) * oc + o));
    __builtin_nontemporal_store(f2{mvs0, mvs1}, (f2*)(vstr + (b3 + 1) * oc + o));
    __builtin_nontemporal_store(f2{mws0, mws1}, (f2*)(vstr + (b3 + 2) * oc + o));
    __builtin_nontemporal_store(f2{mup0 + mus0, mup1 + mus1}, (f2*)(vel + (b3 + 0) * oc + o));
    __builtin_nontemporal_store(f2{mvp0 + mvs0, mvp1 + mvs1}, (f2*)(vel + (b3 + 1) * oc + o));
    __builtin_nontemporal_store(f2{mwp0 + mws0, mwp1 + mws1}, (f2*)(vel + (b3 + 2) * oc + o));
}

extern "C" void kernel_launch(void* const* d_in, const int* in_sizes, int n_in,
                              void* d_out, int out_size, void* d_ws, size_t ws_size,
                              hipStream_t stream)
{
    const float* prev = (const float*)d_in[0];
    const float* nxt  = (const float*)d_in[1];
    const float* phi  = (const float*)d_in[2];
    const float* stm  = (const float*)d_in[3];

    float* out = (float*)d_out;
    const size_t corr_sz = (size_t)CB * 27 * CX * CY * CZ;   // 23,887,872
    const size_t vel_sz  = (size_t)CB * 3 * O * O * O;       // 19,934,016
    float* corr = out;
    float* vel  = out + corr_sz;
    float* vphi = vel + vel_sz;
    float* vstr = vphi + vel_sz;

    {
        constexpr int nwg = (CB * CX * CY * (CZ / 2)) / 256; // 1728
        corr_kernel<<<nwg, 256, 0, stream>>>(prev, nxt, corr);
    }
    {
        const int total = CB * O * O * (O / 2);              // 3,322,336
        const int nwg = (total + 255) / 256;                 // 12978
        vel_kernel<<<nwg, 256, 0, stream>>>(phi, stm, vel, vphi, vstr);
    }
}